// Round 1
// baseline (125.445 us; speedup 1.0000x reference)
//
#include <hip/hip_runtime.h>
#include <hip/hip_bf16.h>
#include <stdint.h>

#define AS1 __attribute__((address_space(1)))
#define AS3 __attribute__((address_space(3)))

typedef short s16x8 __attribute__((ext_vector_type(8)));
typedef float f32x4 __attribute__((ext_vector_type(4)));
typedef unsigned int u32;

static constexpr int NROW = 8192;   // 2B
static constexpr int DDIM = 256;
static constexpr float TEN_LOG2E = 14.4269504088896340736f; // 10 * log2(e)

// ---------------- Kernel 1: row-normalize p = [z_i; z_j], cast to bf16 ----------------
__global__ __launch_bounds__(256) void normalize_bf16_kernel(
    const float* __restrict__ zi, const float* __restrict__ zj,
    ushort* __restrict__ pn)
{
    const int row  = blockIdx.x * 4 + (threadIdx.x >> 6);
    const int lane = threadIdx.x & 63;
    const float* src = (row < 4096) ? (zi + (size_t)row * DDIM)
                                    : (zj + (size_t)(row - 4096) * DDIM);
    float4 v = ((const float4*)src)[lane];
    float ss = v.x * v.x + v.y * v.y + v.z * v.z + v.w * v.w;
    #pragma unroll
    for (int off = 32; off > 0; off >>= 1) ss += __shfl_xor(ss, off, 64);
    const float inv = 1.0f / fmaxf(sqrtf(ss), 1e-8f);

    __hip_bfloat16 b0 = __float2bfloat16(v.x * inv);
    __hip_bfloat16 b1 = __float2bfloat16(v.y * inv);
    __hip_bfloat16 b2 = __float2bfloat16(v.z * inv);
    __hip_bfloat16 b3 = __float2bfloat16(v.w * inv);
    ushort4 o;
    o.x = __builtin_bit_cast(unsigned short, b0);
    o.y = __builtin_bit_cast(unsigned short, b1);
    o.z = __builtin_bit_cast(unsigned short, b2);
    o.w = __builtin_bit_cast(unsigned short, b3);
    ((ushort4*)(pn + (size_t)row * DDIM))[lane] = o;
}

// ---------------- Kernel 2: Gram tiles + fused exp row-sum (no sim materialization) ---
// Grid: (8 chunks of 1024 cols, 64 row-tiles of 128 rows). Block: 256 threads (4 waves).
// Each block: rows [r0, r0+128) x cols [chunk*1024, +1024), accumulating
// partial_s[row] = sum_{j in chunk, j != row} exp(10 * cos(row, j)), and writing
// pos[row] = 10*cos(row, row^4096) when the chunk contains that column tile.
__global__ __launch_bounds__(256, 2) void simexp_kernel(
    const ushort* __restrict__ pn,
    float* __restrict__ partial_s,
    float* __restrict__ pos_out)
{
    __shared__ __align__(16) ushort ldsA[128 * 32];
    __shared__ __align__(16) ushort ldsB[128 * 32];
    __shared__ float lds_rs[2][128];

    const int tid  = threadIdx.x;
    const int w    = tid >> 6;     // wave id 0..3
    const int lane = tid & 63;
    const int q    = lane >> 4;    // quad 0..3
    const int l15  = lane & 15;
    const int wm   = (w >> 1) * 64;  // wave row offset in 128x128 tile
    const int wn   = (w & 1) * 64;   // wave col offset

    const int chunk = blockIdx.x;    // 0..7
    const int tile  = blockIdx.y;    // 0..63
    const int r0    = tile * 128;

    // staging: per wave, 2 calls per tile stage; lane l covers row (l>>2), 8-elem chunk (l&3)
    const int srow = w * 16 + (lane >> 2);
    const int scol = (lane & 3) * 8;

    float rsum[4][4];
    #pragma unroll
    for (int mi = 0; mi < 4; ++mi)
        #pragma unroll
        for (int r = 0; r < 4; ++r) rsum[mi][r] = 0.0f;

    for (int jt = 0; jt < 8; ++jt) {
        const int c0 = chunk * 1024 + jt * 128;

        f32x4 acc[4][4];
        #pragma unroll
        for (int mi = 0; mi < 4; ++mi)
            #pragma unroll
            for (int ni = 0; ni < 4; ++ni)
                acc[mi][ni] = (f32x4){0.f, 0.f, 0.f, 0.f};

        for (int kt = 0; kt < 8; ++kt) {
            const int k0 = kt * 32;
            #pragma unroll
            for (int cc = 0; cc < 2; ++cc) {
                const ushort* gA = pn + (size_t)(r0 + cc * 64 + srow) * DDIM + k0 + scol;
                const ushort* gB = pn + (size_t)(c0 + cc * 64 + srow) * DDIM + k0 + scol;
                ushort* lA = ldsA + (cc * 64 + w * 16) * 32;  // wave-uniform base
                ushort* lB = ldsB + (cc * 64 + w * 16) * 32;
                __builtin_amdgcn_global_load_lds((const AS1 u32*)gA, (AS3 u32*)lA, 16, 0, 0);
                __builtin_amdgcn_global_load_lds((const AS1 u32*)gB, (AS3 u32*)lB, 16, 0, 0);
            }
            __syncthreads();

            s16x8 af[4], bfr[4];
            #pragma unroll
            for (int mi = 0; mi < 4; ++mi)
                af[mi] = *(const s16x8*)(ldsA + (wm + mi * 16 + l15) * 32 + q * 8);
            #pragma unroll
            for (int ni = 0; ni < 4; ++ni)
                bfr[ni] = *(const s16x8*)(ldsB + (wn + ni * 16 + l15) * 32 + q * 8);

            #pragma unroll
            for (int mi = 0; mi < 4; ++mi)
                #pragma unroll
                for (int ni = 0; ni < 4; ++ni)
                    acc[mi][ni] = __builtin_amdgcn_mfma_f32_16x16x32_bf16(
                        af[mi], bfr[ni], acc[mi][ni], 0, 0, 0);
            __syncthreads();
        }

        // epilogue: exp and accumulate row sums (C/D layout: col=lane&15, row=q*4+reg)
        #pragma unroll
        for (int mi = 0; mi < 4; ++mi)
            #pragma unroll
            for (int ni = 0; ni < 4; ++ni)
                #pragma unroll
                for (int r = 0; r < 4; ++r)
                    rsum[mi][r] += exp2f(acc[mi][ni][r] * TEN_LOG2E);

        if (c0 == r0) {  // diagonal tile: subtract self-similarity terms (exact cancel)
            #pragma unroll
            for (int mi = 0; mi < 4; ++mi)
                #pragma unroll
                for (int ni = 0; ni < 4; ++ni)
                    #pragma unroll
                    for (int r = 0; r < 4; ++r) {
                        const int lr = wm + mi * 16 + q * 4 + r;
                        const int lc = wn + ni * 16 + l15;
                        if (lr == lc)
                            rsum[mi][r] -= exp2f(acc[mi][ni][r] * TEN_LOG2E);
                    }
        }
        if (c0 == (r0 ^ 4096)) {  // positive-pair tile: record pos = 10*cos
            #pragma unroll
            for (int mi = 0; mi < 4; ++mi)
                #pragma unroll
                for (int ni = 0; ni < 4; ++ni)
                    #pragma unroll
                    for (int r = 0; r < 4; ++r) {
                        const int lr = wm + mi * 16 + q * 4 + r;
                        const int lc = wn + ni * 16 + l15;
                        if (lr == lc)
                            pos_out[r0 + lr] = acc[mi][ni][r] * 10.0f;
                    }
        }
    }

    // reduce row partial sums across the 16 lanes of each quad (cols live on l15)
    #pragma unroll
    for (int mi = 0; mi < 4; ++mi)
        #pragma unroll
        for (int r = 0; r < 4; ++r) {
            float v = rsum[mi][r];
            v += __shfl_xor(v, 1, 64);
            v += __shfl_xor(v, 2, 64);
            v += __shfl_xor(v, 4, 64);
            v += __shfl_xor(v, 8, 64);
            rsum[mi][r] = v;
        }
    if (l15 == 0) {
        #pragma unroll
        for (int mi = 0; mi < 4; ++mi)
            #pragma unroll
            for (int r = 0; r < 4; ++r)
                lds_rs[w & 1][wm + mi * 16 + q * 4 + r] = rsum[mi][r];
    }
    __syncthreads();
    if (tid < 128)
        partial_s[((size_t)tile * 8 + chunk) * 128 + tid] =
            lds_rs[0][tid] + lds_rs[1][tid];
}

// ---------------- Kernel 3: finalize loss ----------------
__global__ __launch_bounds__(256) void finalize_kernel(
    const float* __restrict__ partial_s, const float* __restrict__ pos,
    float* __restrict__ out)
{
    const int tid = threadIdx.x;
    float local = 0.0f;
    for (int i = tid; i < NROW; i += 256) {
        const int tile = i >> 7, lr = i & 127;
        const float* p = partial_s + ((size_t)tile * 8) * 128 + lr;
        float s = 0.0f;
        #pragma unroll
        for (int c = 0; c < 8; ++c) s += p[c * 128];
        local += __logf(s) - pos[i];
    }
    #pragma unroll
    for (int off = 32; off > 0; off >>= 1) local += __shfl_xor(local, off, 64);
    __shared__ float red[4];
    if ((tid & 63) == 0) red[tid >> 6] = local;
    __syncthreads();
    if (tid == 0) out[0] = (red[0] + red[1] + red[2] + red[3]) * (1.0f / 8192.0f);
}

// ---------------- Launch ----------------
extern "C" void kernel_launch(void* const* d_in, const int* in_sizes, int n_in,
                              void* d_out, int out_size, void* d_ws, size_t ws_size,
                              hipStream_t stream)
{
    const float* zi = (const float*)d_in[0];
    const float* zj = (const float*)d_in[1];

    ushort* pn      = (ushort*)d_ws;                                   // 4 MB bf16 normalized rows
    float* partial  = (float*)((char*)d_ws + (4u << 20));              // 64*8*128 fp32 = 256 KB
    float* pos      = (float*)((char*)d_ws + (4u << 20) + (256u << 10)); // 8192 fp32 = 32 KB
    float* out      = (float*)d_out;

    hipLaunchKernelGGL(normalize_bf16_kernel, dim3(2048), dim3(256), 0, stream, zi, zj, pn);
    hipLaunchKernelGGL(simexp_kernel, dim3(8, 64), dim3(256), 0, stream, pn, partial, pos);
    hipLaunchKernelGGL(finalize_kernel, dim3(1), dim3(256), 0, stream, partial, pos, out);
}

// Round 2
// 115.990 us; speedup vs baseline: 1.0815x; 1.0815x over previous
//
#include <hip/hip_runtime.h>
#include <hip/hip_bf16.h>
#include <stdint.h>

#define AS1 __attribute__((address_space(1)))
#define AS3 __attribute__((address_space(3)))

typedef short s16x8 __attribute__((ext_vector_type(8)));
typedef float f32x4 __attribute__((ext_vector_type(4)));
typedef unsigned int u32;

static constexpr int NROW = 8192;   // 2B
static constexpr int DDIM = 256;
static constexpr float TEN_LOG2E = 14.4269504088896340736f; // 10 * log2(e)

// ---------------- Kernel 1: row-normalize p = [z_i; z_j], cast to bf16 ----------------
// Also zero-inits row_s[8192] (blocks 0..7) and out[0] (block 0) — d_ws/d_out are
// poisoned 0xAA before every launch.
__global__ __launch_bounds__(256) void normalize_bf16_kernel(
    const float* __restrict__ zi, const float* __restrict__ zj,
    ushort* __restrict__ pn, float* __restrict__ row_s, float* __restrict__ out)
{
    if (blockIdx.x < 8) {
        // zero 8192 floats: 8 blocks x 256 threads x float4
        ((float4*)row_s)[blockIdx.x * 256 + threadIdx.x] = (float4){0.f, 0.f, 0.f, 0.f};
        if (blockIdx.x == 0 && threadIdx.x == 0) out[0] = 0.0f;
    }

    const int row  = blockIdx.x * 4 + (threadIdx.x >> 6);
    const int lane = threadIdx.x & 63;
    const float* src = (row < 4096) ? (zi + (size_t)row * DDIM)
                                    : (zj + (size_t)(row - 4096) * DDIM);
    float4 v = ((const float4*)src)[lane];
    float ss = v.x * v.x + v.y * v.y + v.z * v.z + v.w * v.w;
    #pragma unroll
    for (int off = 32; off > 0; off >>= 1) ss += __shfl_xor(ss, off, 64);
    const float inv = 1.0f / fmaxf(sqrtf(ss), 1e-8f);

    __hip_bfloat16 b0 = __float2bfloat16(v.x * inv);
    __hip_bfloat16 b1 = __float2bfloat16(v.y * inv);
    __hip_bfloat16 b2 = __float2bfloat16(v.z * inv);
    __hip_bfloat16 b3 = __float2bfloat16(v.w * inv);
    ushort4 o;
    o.x = __builtin_bit_cast(unsigned short, b0);
    o.y = __builtin_bit_cast(unsigned short, b1);
    o.z = __builtin_bit_cast(unsigned short, b2);
    o.w = __builtin_bit_cast(unsigned short, b3);
    ((ushort4*)(pn + (size_t)row * DDIM))[lane] = o;
}

// ---------------- Kernel 2: one 128x128 Gram tile per block + fused exp row-sum -------
// Grid: (64 col-tiles, 64 row-tiles), block 256 threads (4 waves).
// Each block accumulates sum_j exp(10*cos(r,c)) over its tile (diag masked when on the
// diagonal tile), atomicAdds the 128 row partial sums into row_s, and writes
// pos[r] = 10*cos(r, r^4096) when this tile contains the positive pair column.
__global__ __launch_bounds__(256, 2) void simexp_kernel(
    const ushort* __restrict__ pn,
    float* __restrict__ row_s,
    float* __restrict__ pos_out)
{
    __shared__ __align__(16) ushort ldsA[128 * 32];
    __shared__ __align__(16) ushort ldsB[128 * 32];
    __shared__ float lds_rs[2][128];

    const int tid  = threadIdx.x;
    const int w    = tid >> 6;     // wave id 0..3
    const int lane = tid & 63;
    const int q    = lane >> 4;    // quad 0..3
    const int l15  = lane & 15;
    const int wm   = (w >> 1) * 64;  // wave row offset in 128x128 tile
    const int wn   = (w & 1) * 64;   // wave col offset

    const int c0 = blockIdx.x * 128;
    const int r0 = blockIdx.y * 128;

    // staging: per wave, lane l covers row (l>>2), 8-elem chunk (l&3)
    const int srow = w * 16 + (lane >> 2);
    const int scol = (lane & 3) * 8;

    float rsum[4][4];
    #pragma unroll
    for (int mi = 0; mi < 4; ++mi)
        #pragma unroll
        for (int r = 0; r < 4; ++r) rsum[mi][r] = 0.0f;

    f32x4 acc[4][4];
    #pragma unroll
    for (int mi = 0; mi < 4; ++mi)
        #pragma unroll
        for (int ni = 0; ni < 4; ++ni)
            acc[mi][ni] = (f32x4){0.f, 0.f, 0.f, 0.f};

    for (int kt = 0; kt < 8; ++kt) {
        const int k0 = kt * 32;
        #pragma unroll
        for (int cc = 0; cc < 2; ++cc) {
            const ushort* gA = pn + (size_t)(r0 + cc * 64 + srow) * DDIM + k0 + scol;
            const ushort* gB = pn + (size_t)(c0 + cc * 64 + srow) * DDIM + k0 + scol;
            ushort* lA = ldsA + (cc * 64 + w * 16) * 32;  // wave-uniform base
            ushort* lB = ldsB + (cc * 64 + w * 16) * 32;
            __builtin_amdgcn_global_load_lds((const AS1 u32*)gA, (AS3 u32*)lA, 16, 0, 0);
            __builtin_amdgcn_global_load_lds((const AS1 u32*)gB, (AS3 u32*)lB, 16, 0, 0);
        }
        __syncthreads();

        s16x8 af[4], bfr[4];
        #pragma unroll
        for (int mi = 0; mi < 4; ++mi)
            af[mi] = *(const s16x8*)(ldsA + (wm + mi * 16 + l15) * 32 + q * 8);
        #pragma unroll
        for (int ni = 0; ni < 4; ++ni)
            bfr[ni] = *(const s16x8*)(ldsB + (wn + ni * 16 + l15) * 32 + q * 8);

        #pragma unroll
        for (int mi = 0; mi < 4; ++mi)
            #pragma unroll
            for (int ni = 0; ni < 4; ++ni)
                acc[mi][ni] = __builtin_amdgcn_mfma_f32_16x16x32_bf16(
                    af[mi], bfr[ni], acc[mi][ni], 0, 0, 0);
        __syncthreads();
    }

    // epilogue: exp and accumulate row sums (C/D layout: col=lane&15, row=q*4+reg)
    #pragma unroll
    for (int mi = 0; mi < 4; ++mi)
        #pragma unroll
        for (int ni = 0; ni < 4; ++ni)
            #pragma unroll
            for (int r = 0; r < 4; ++r)
                rsum[mi][r] += exp2f(acc[mi][ni][r] * TEN_LOG2E);

    if (c0 == r0) {  // diagonal tile: subtract self-similarity terms (exact cancel)
        #pragma unroll
        for (int mi = 0; mi < 4; ++mi)
            #pragma unroll
            for (int ni = 0; ni < 4; ++ni)
                #pragma unroll
                for (int r = 0; r < 4; ++r) {
                    const int lr = wm + mi * 16 + q * 4 + r;
                    const int lc = wn + ni * 16 + l15;
                    if (lr == lc)
                        rsum[mi][r] -= exp2f(acc[mi][ni][r] * TEN_LOG2E);
                }
    }
    if (c0 == (r0 ^ 4096)) {  // positive-pair tile: record pos = 10*cos
        #pragma unroll
        for (int mi = 0; mi < 4; ++mi)
            #pragma unroll
            for (int ni = 0; ni < 4; ++ni)
                #pragma unroll
                for (int r = 0; r < 4; ++r) {
                    const int lr = wm + mi * 16 + q * 4 + r;
                    const int lc = wn + ni * 16 + l15;
                    if (lr == lc)
                        pos_out[r0 + lr] = acc[mi][ni][r] * 10.0f;
                }
    }

    // reduce row partial sums across the 16 lanes of each quad (cols live on l15)
    #pragma unroll
    for (int mi = 0; mi < 4; ++mi)
        #pragma unroll
        for (int r = 0; r < 4; ++r) {
            float v = rsum[mi][r];
            v += __shfl_xor(v, 1, 64);
            v += __shfl_xor(v, 2, 64);
            v += __shfl_xor(v, 4, 64);
            v += __shfl_xor(v, 8, 64);
            rsum[mi][r] = v;
        }
    if (l15 == 0) {
        #pragma unroll
        for (int mi = 0; mi < 4; ++mi)
            #pragma unroll
            for (int r = 0; r < 4; ++r)
                lds_rs[w & 1][wm + mi * 16 + q * 4 + r] = rsum[mi][r];
    }
    __syncthreads();
    if (tid < 128)
        atomicAdd(&row_s[r0 + tid], lds_rs[0][tid] + lds_rs[1][tid]);
}

// ---------------- Kernel 3: finalize loss ----------------
// 8 blocks x 256 threads, 4 rows/thread via float4; coalesced reads of row_s/pos.
__global__ __launch_bounds__(256) void finalize_kernel(
    const float* __restrict__ row_s, const float* __restrict__ pos,
    float* __restrict__ out)
{
    const int i = blockIdx.x * 256 + threadIdx.x;   // float4 index, 2048 total
    float4 s = ((const float4*)row_s)[i];
    float4 p = ((const float4*)pos)[i];
    float local = (__logf(s.x) - p.x) + (__logf(s.y) - p.y)
                + (__logf(s.z) - p.z) + (__logf(s.w) - p.w);
    #pragma unroll
    for (int off = 32; off > 0; off >>= 1) local += __shfl_xor(local, off, 64);
    __shared__ float red[4];
    if ((threadIdx.x & 63) == 0) red[threadIdx.x >> 6] = local;
    __syncthreads();
    if (threadIdx.x == 0)
        atomicAdd(out, (red[0] + red[1] + red[2] + red[3]) * (1.0f / 8192.0f));
}

// ---------------- Launch ----------------
extern "C" void kernel_launch(void* const* d_in, const int* in_sizes, int n_in,
                              void* d_out, int out_size, void* d_ws, size_t ws_size,
                              hipStream_t stream)
{
    const float* zi = (const float*)d_in[0];
    const float* zj = (const float*)d_in[1];

    ushort* pn   = (ushort*)d_ws;                                    // 4 MB bf16 normalized rows
    float* row_s = (float*)((char*)d_ws + (4u << 20));               // 8192 fp32 = 32 KB
    float* pos   = (float*)((char*)d_ws + (4u << 20) + (32u << 10)); // 8192 fp32 = 32 KB
    float* out   = (float*)d_out;

    hipLaunchKernelGGL(normalize_bf16_kernel, dim3(2048), dim3(256), 0, stream,
                       zi, zj, pn, row_s, out);
    hipLaunchKernelGGL(simexp_kernel, dim3(64, 64), dim3(256), 0, stream, pn, row_s, pos);
    hipLaunchKernelGGL(finalize_kernel, dim3(8), dim3(256), 0, stream, row_s, pos, out);
}